// Round 1
// baseline (1008.111 us; speedup 1.0000x reference)
//
#include <hip/hip_runtime.h>
#include <hip/hip_bf16.h>

#define PP     128   // time steps
#define NNODE  256   // nodes
#define DMODEL 128
#define DIN    256
#define LSTR   136   // LDS row stride (bf16 elems): +8 pad -> 2-way-free banking
#define NEGINF -65504.0f

typedef __attribute__((ext_vector_type(4))) float          f32x4;
typedef __attribute__((ext_vector_type(8))) __bf16         bf16x8;
typedef __attribute__((ext_vector_type(8))) unsigned short u16x8;

static __device__ __forceinline__ unsigned short f2b(float f) {
  union { float f; unsigned u; } x; x.f = f;
  unsigned r = x.u + 0x7fffu + ((x.u >> 16) & 1u);   // RNE
  return (unsigned short)(r >> 16);
}

static __device__ __forceinline__ f32x4 zero4() {
  f32x4 v = {0.f, 0.f, 0.f, 0.f};
  return v;
}

static __device__ __forceinline__ bf16x8 zero_bf8() {
  u16x8 v = {0, 0, 0, 0, 0, 0, 0, 0};
  return __builtin_bit_cast(bf16x8, v);
}

static __device__ __forceinline__ bf16x8 ld_bf8(const unsigned short* p) {
  u16x8 v = *(const u16x8*)p;
  return __builtin_bit_cast(bf16x8, v);
}

static __device__ __forceinline__ f32x4 mfma16(bf16x8 a, bf16x8 b, f32x4 c) {
  return __builtin_amdgcn_mfma_f32_16x16x32_bf16(a, b, c, 0, 0, 0);
}

// ---------------------------------------------------------------------------
// Prep: transpose + bf16-convert weights into ws.
// Layout (bf16 elems): WqT[128][256] @0, WkT @32768, WvT @65536,
//                      W1T[128][128] @98304, W2T @114688.  WT[n][k] = W[k][n].
// ---------------------------------------------------------------------------
__global__ void prep_weights(const float* __restrict__ Wq, const float* __restrict__ Wk,
                             const float* __restrict__ Wv, const float* __restrict__ W1,
                             const float* __restrict__ W2, unsigned short* __restrict__ ws) {
  int idx = blockIdx.x * blockDim.x + threadIdx.x;
  if (idx < 98304) {                       // Wq/Wk/Wv : (256,128) -> [128][256]
    int seg = idx >> 15;                   // /32768
    int r   = idx & 32767;
    int n   = r >> 8;                      // out row
    int k   = r & 255;
    const float* W = (seg == 0) ? Wq : (seg == 1) ? Wk : Wv;
    ws[idx] = f2b(W[k * DMODEL + n]);
  } else if (idx < 131072) {               // W1/W2 : (128,128) -> [128][128]
    int r   = idx - 98304;
    int seg = r >> 14;
    int rr  = r & 16383;
    int n   = rr >> 7;
    int k   = rr & 127;
    const float* W = (seg == 0) ? W1 : W2;
    ws[idx] = f2b(W[k * DMODEL + n]);
  }
}

// ---------------------------------------------------------------------------
// Fused: one block per (b, n). 512 threads = 8 waves.
//  wave w owns C-rows [16w, 16w+16) of every 128-row GEMM in the block.
// ---------------------------------------------------------------------------
__global__ __launch_bounds__(512, 2) void fused_attn(
    const float* __restrict__ X, const float* __restrict__ STE,
    const unsigned short* __restrict__ Wt,
    const float* __restrict__ bq, const float* __restrict__ bk,
    const float* __restrict__ bv, const float* __restrict__ b1,
    const float* __restrict__ b2, float* __restrict__ out) {
  __shared__ __align__(16) unsigned short s_x[PP * LSTR];  // x_ chunk / probs / att
  __shared__ __align__(16) unsigned short s_q[PP * LSTR];  // q[p][f]
  __shared__ __align__(16) unsigned short s_k[PP * LSTR];  // k[p][f], later h1[p][f]
  __shared__ __align__(16) unsigned short s_v[PP * LSTR];  // vT[f][p]

  const unsigned short* WqT = Wt;
  const unsigned short* WkT = Wt + 32768;
  const unsigned short* WvT = Wt + 65536;
  const unsigned short* W1T = Wt + 98304;
  const unsigned short* W2T = Wt + 114688;

  const int bid  = blockIdx.x;
  const int bb   = bid >> 8;           // batch
  const int nn   = bid & 255;          // node
  const int tid  = threadIdx.x;
  const int wv   = tid >> 6;
  const int lane = tid & 63;
  const int quad = lane >> 4;
  const int l16  = lane & 15;
  const int mrow  = wv * 16 + l16;     // A-fragment row this lane loads
  const int crow0 = wv * 16 + quad * 4;// first C row this lane owns

  // ---------------- Stage 1: QKV projection (K = 256 in two 128 chunks) ----
  f32x4 accQ[8], accK[8], accV[8];
#pragma unroll
  for (int i = 0; i < 8; ++i) { accQ[i] = zero4(); accK[i] = zero4(); accV[i] = zero4(); }

  for (int chunk = 0; chunk < 2; ++chunk) {
    const float* src = chunk ? STE : X;
    {
      const int r0 = tid >> 5;
      const int c4 = (tid & 31) << 2;
#pragma unroll
      for (int it = 0; it < 8; ++it) {
        const int row = it * 16 + r0;
        const float4 v =
            *(const float4*)(src + (size_t)((bb * PP + row) * NNODE + nn) * DMODEL + c4);
        unsigned short* d = &s_x[row * LSTR + c4];
        d[0] = f2b(v.x); d[1] = f2b(v.y); d[2] = f2b(v.z); d[3] = f2b(v.w);
      }
    }
    __syncthreads();

    bf16x8 af[4];
#pragma unroll
    for (int ks = 0; ks < 4; ++ks)
      af[ks] = ld_bf8(&s_x[mrow * LSTR + ks * 32 + quad * 8]);

#pragma unroll
    for (int m = 0; m < 3; ++m) {
      const unsigned short* W =
          ((m == 0) ? WqT : (m == 1) ? WkT : WvT) + chunk * 128 + quad * 8;
      f32x4* acc = (m == 0) ? accQ : (m == 1) ? accK : accV;
#pragma unroll
      for (int ct = 0; ct < 8; ++ct) {
        const unsigned short* wr = W + (ct * 16 + l16) * DIN;
#pragma unroll
        for (int ks = 0; ks < 4; ++ks)
          acc[ct] = mfma16(af[ks], ld_bf8(wr + ks * 32), acc[ct]);
      }
    }
    __syncthreads();   // all waves done with s_x before next chunk overwrites
  }

  // bias + relu + store q,k (row-major) and v (transposed) to LDS
#pragma unroll
  for (int m = 0; m < 3; ++m) {
    const float* bias = (m == 0) ? bq : (m == 1) ? bk : bv;
    f32x4* acc = (m == 0) ? accQ : (m == 1) ? accK : accV;
#pragma unroll
    for (int ct = 0; ct < 8; ++ct) {
      const int col = ct * 16 + l16;
      const float bsc = bias[col];
#pragma unroll
      for (int r = 0; r < 4; ++r) {
        float v = acc[ct][r] + bsc;
        v = v > 0.f ? v : 0.f;
        const unsigned short h = f2b(v);
        const int row = crow0 + r;
        if (m == 0)      s_q[row * LSTR + col] = h;
        else if (m == 1) s_k[row * LSTR + col] = h;
        else             s_v[col * LSTR + row] = h;   // vT[d][p]
      }
    }
  }
  __syncthreads();

  // ---------------- Stage 2: per-head causal attention ---------------------
  f32x4 attA[8];
#pragma unroll
  for (int i = 0; i < 8; ++i) attA[i] = zero4();

  for (int h = 0; h < 8; ++h) {
    // S = q_h @ k_h^T, K padded 16->32 (quads 2,3 zero)
    bf16x8 aq = (quad < 2) ? ld_bf8(&s_q[mrow * LSTR + h * 16 + quad * 8]) : zero_bf8();
    f32x4 s[8];
#pragma unroll
    for (int ct = 0; ct < 8; ++ct) {
      bf16x8 bk8 =
          (quad < 2) ? ld_bf8(&s_k[(ct * 16 + l16) * LSTR + h * 16 + quad * 8]) : zero_bf8();
      s[ct] = mfma16(aq, bk8, zero4());
    }
    // scale + causal mask + row softmax (wave owns full rows; reduce over 16-lane group)
#pragma unroll
    for (int r = 0; r < 4; ++r) {
      const int prow = crow0 + r;
      float mx = NEGINF;
#pragma unroll
      for (int ct = 0; ct < 8; ++ct) {
        const int cq = ct * 16 + l16;
        float v = s[ct][r] * 0.25f;           // 1/sqrt(16)
        v = (cq <= prow) ? v : NEGINF;
        s[ct][r] = v;
        mx = fmaxf(mx, v);
      }
#pragma unroll
      for (int off = 1; off < 16; off <<= 1) mx = fmaxf(mx, __shfl_xor(mx, off, 64));
      float sum = 0.f;
#pragma unroll
      for (int ct = 0; ct < 8; ++ct) {
        float e = __expf(s[ct][r] - mx);
        s[ct][r] = e;
        sum += e;
      }
#pragma unroll
      for (int off = 1; off < 16; off <<= 1) sum += __shfl_xor(sum, off, 64);
      const float inv = 1.0f / sum;
#pragma unroll
      for (int ct = 0; ct < 8; ++ct) s[ct][r] *= inv;
    }
    __syncthreads();   // previous head's PV reads of s_x complete
#pragma unroll
    for (int ct = 0; ct < 8; ++ct) {
      const int cq = ct * 16 + l16;
#pragma unroll
      for (int r = 0; r < 4; ++r)
        s_x[(crow0 + r) * LSTR + cq] = f2b(s[ct][r]);   // probs, C-layout -> [p][q]
    }
    __syncthreads();
    // PV: attended_h = probs @ v_h   (A from probs LDS, B from vT rows)
#pragma unroll
    for (int ks = 0; ks < 4; ++ks) {
      bf16x8 ap  = ld_bf8(&s_x[mrow * LSTR + ks * 32 + quad * 8]);
      bf16x8 bv8 = ld_bf8(&s_v[(h * 16 + l16) * LSTR + ks * 32 + quad * 8]);
      attA[h] = mfma16(ap, bv8, attA[h]);
    }
  }
  __syncthreads();   // last PV done; s_x now reused for att

  // att regs -> LDS [p][f]
#pragma unroll
  for (int h = 0; h < 8; ++h) {
    const int col = h * 16 + l16;
#pragma unroll
    for (int r = 0; r < 4; ++r)
      s_x[(crow0 + r) * LSTR + col] = f2b(attA[h][r]);
  }
  __syncthreads();

  // ---------------- Stage 3: MLP ------------------------------------------
  f32x4 acc1[8];
#pragma unroll
  for (int i = 0; i < 8; ++i) acc1[i] = zero4();
  {
    bf16x8 af[4];
#pragma unroll
    for (int ks = 0; ks < 4; ++ks)
      af[ks] = ld_bf8(&s_x[mrow * LSTR + ks * 32 + quad * 8]);
#pragma unroll
    for (int ct = 0; ct < 8; ++ct) {
      const unsigned short* wr = W1T + (ct * 16 + l16) * DMODEL + quad * 8;
#pragma unroll
      for (int ks = 0; ks < 4; ++ks)
        acc1[ct] = mfma16(af[ks], ld_bf8(wr + ks * 32), acc1[ct]);
    }
  }
#pragma unroll
  for (int ct = 0; ct < 8; ++ct) {
    const int col = ct * 16 + l16;
    const float bsc = b1[col];
#pragma unroll
    for (int r = 0; r < 4; ++r) {
      float v = acc1[ct][r] + bsc;
      v = v > 0.f ? v : 0.f;
      s_k[(crow0 + r) * LSTR + col] = f2b(v);   // h1 reuses k buffer
    }
  }
  __syncthreads();

  f32x4 acc2[8];
#pragma unroll
  for (int i = 0; i < 8; ++i) acc2[i] = zero4();
  {
    bf16x8 af[4];
#pragma unroll
    for (int ks = 0; ks < 4; ++ks)
      af[ks] = ld_bf8(&s_k[mrow * LSTR + ks * 32 + quad * 8]);
#pragma unroll
    for (int ct = 0; ct < 8; ++ct) {
      const unsigned short* wr = W2T + (ct * 16 + l16) * DMODEL + quad * 8;
#pragma unroll
      for (int ks = 0; ks < 4; ++ks)
        acc2[ct] = mfma16(af[ks], ld_bf8(wr + ks * 32), acc2[ct]);
    }
  }
  // + b2, store fp32 out[b][p][n][col]
#pragma unroll
  for (int ct = 0; ct < 8; ++ct) {
    const int col = ct * 16 + l16;
    const float bsc = b2[col];
#pragma unroll
    for (int r = 0; r < 4; ++r) {
      const int row = crow0 + r;
      out[(size_t)((bb * PP + row) * NNODE + nn) * DMODEL + col] = acc2[ct][r] + bsc;
    }
  }
}

extern "C" void kernel_launch(void* const* d_in, const int* in_sizes, int n_in,
                              void* d_out, int out_size, void* d_ws, size_t ws_size,
                              hipStream_t stream) {
  const float* X   = (const float*)d_in[0];
  const float* STE = (const float*)d_in[1];
  const float* Wq  = (const float*)d_in[2];
  const float* bq  = (const float*)d_in[3];
  const float* Wk  = (const float*)d_in[4];
  const float* bk  = (const float*)d_in[5];
  const float* Wv  = (const float*)d_in[6];
  const float* bv  = (const float*)d_in[7];
  const float* W1  = (const float*)d_in[8];
  const float* b1  = (const float*)d_in[9];
  const float* W2  = (const float*)d_in[10];
  const float* b2  = (const float*)d_in[11];
  float* out = (float*)d_out;
  unsigned short* ws = (unsigned short*)d_ws;

  prep_weights<<<512, 256, 0, stream>>>(Wq, Wk, Wv, W1, W2, ws);
  fused_attn<<<2048, 512, 0, stream>>>(X, STE, ws, bq, bk, bv, b1, b2, out);
}

// Round 3
// 907.214 us; speedup vs baseline: 1.1112x; 1.1112x over previous
//
#include <hip/hip_runtime.h>
#include <hip/hip_bf16.h>

#define PP     128   // time steps
#define NNODE  256   // nodes
#define DMODEL 128
#define DIN    256
#define NEGINF -65504.0f

#define WOFF 131072            // weight area (ushort elems)
#define PB   4194304           // per-batch per-tensor elems = P*N*D

typedef __attribute__((ext_vector_type(4))) float          f32x4;
typedef __attribute__((ext_vector_type(8))) __bf16         bf16x8;
typedef __attribute__((ext_vector_type(8))) unsigned short u16x8;

static __device__ __forceinline__ unsigned short f2b(float f) {
  union { float f; unsigned u; } x; x.f = f;
  unsigned r = x.u + 0x7fffu + ((x.u >> 16) & 1u);   // RNE
  return (unsigned short)(r >> 16);
}
static __device__ __forceinline__ f32x4 zero4() {
  f32x4 v = {0.f, 0.f, 0.f, 0.f};
  return v;
}
static __device__ __forceinline__ bf16x8 zero_bf8() {
  u16x8 v = {0, 0, 0, 0, 0, 0, 0, 0};
  return __builtin_bit_cast(bf16x8, v);
}
static __device__ __forceinline__ bf16x8 ld_bf8(const unsigned short* p) {
  u16x8 v = *(const u16x8*)p;
  return __builtin_bit_cast(bf16x8, v);
}
static __device__ __forceinline__ f32x4 mfma16(bf16x8 a, bf16x8 b, f32x4 c) {
  return __builtin_amdgcn_mfma_f32_16x16x32_bf16(a, b, c, 0, 0, 0);
}

// ---------------------------------------------------------------------------
// Prep: transpose + bf16-convert weights into ws.
// WqT[128][256] @0, WkT @32768, WvT @65536, W1T[128][128] @98304, W2T @114688
// ---------------------------------------------------------------------------
__global__ void prep_weights(const float* __restrict__ Wq, const float* __restrict__ Wk,
                             const float* __restrict__ Wv, const float* __restrict__ W1,
                             const float* __restrict__ W2, unsigned short* __restrict__ ws) {
  int idx = blockIdx.x * blockDim.x + threadIdx.x;
  if (idx < 98304) {                       // Wq/Wk/Wv : (256,128) -> [128][256]
    int seg = idx >> 15;
    int r   = idx & 32767;
    int n   = r >> 8;
    int k   = r & 255;
    const float* W = (seg == 0) ? Wq : (seg == 1) ? Wk : Wv;
    ws[idx] = f2b(W[k * DMODEL + n]);
  } else if (idx < 131072) {               // W1/W2 : (128,128) -> [128][128]
    int r   = idx - 98304;
    int seg = r >> 14;
    int rr  = r & 16383;
    int n   = rr >> 7;
    int k   = rr & 127;
    const float* W = (seg == 0) ? W1 : W2;
    ws[idx] = f2b(W[k * DMODEL + n]);
  }
}

// ---------------------------------------------------------------------------
// K1: QKV projection. One block per 128 consecutive n at fixed (b,p).
// qkv layout is node-major: [bl][n][p][f] so K2's per-(b,n) slab is contiguous.
// 1 barrier. LDS 66 KiB -> 2 blocks/CU.
// ---------------------------------------------------------------------------
__global__ __launch_bounds__(512, 4) void qkv_gemm(
    const float* __restrict__ X, const float* __restrict__ STE,
    const unsigned short* __restrict__ Wt,
    const float* __restrict__ bq, const float* __restrict__ bk,
    const float* __restrict__ bv,
    unsigned short* __restrict__ q, unsigned short* __restrict__ k,
    unsigned short* __restrict__ v, int b0) {
  __shared__ __align__(16) unsigned short s_a[128 * 264];   // x_ [n-row][256f], +8 pad

  const int R0 = blockIdx.x << 7;
  const int n0 = R0 & 255;                 // 0 or 128
  const int p  = (R0 >> 8) & 127;
  const int bl = R0 >> 15;                 // local batch within chunk
  const int b  = b0 + bl;                  // global batch
  const int tid = threadIdx.x;

  {  // stage x_ = concat(X, STE): 128 rows x 256 f fp32 -> bf16 LDS
    const int row = tid >> 2;
    const size_t rbase = (size_t)((b * PP + p) * NNODE + n0 + row) * DMODEL;
    const float* xr = X + rbase;
    const float* sr = STE + rbase;
    unsigned short* d = &s_a[row * 264];
#pragma unroll
    for (int i = 0; i < 16; ++i) {
      const int f = ((tid & 3) + i * 4) << 2;   // 0..252 step 4
      const float4 vv = (f < 128) ? *(const float4*)(xr + f)
                                  : *(const float4*)(sr + f - 128);
      d[f] = f2b(vv.x); d[f + 1] = f2b(vv.y); d[f + 2] = f2b(vv.z); d[f + 3] = f2b(vv.w);
    }
  }
  __syncthreads();

  const int wv = tid >> 6, lane = tid & 63, quad = lane >> 4, l16 = lane & 15;
  const int mrow = wv * 16 + l16, crow0 = wv * 16 + quad * 4;

  bf16x8 af[8];
#pragma unroll
  for (int ks = 0; ks < 8; ++ks)
    af[ks] = ld_bf8(&s_a[mrow * 264 + ks * 32 + quad * 8]);

  for (int m = 0; m < 3; ++m) {
    const unsigned short* W = Wt + m * 32768;
    const float* bias = (m == 0) ? bq : (m == 1) ? bk : bv;
    f32x4 acc[8];
#pragma unroll
    for (int i = 0; i < 8; ++i) acc[i] = zero4();
#pragma unroll
    for (int ct = 0; ct < 8; ++ct) {
      const unsigned short* wr = W + (ct * 16 + l16) * DIN + quad * 8;
#pragma unroll
      for (int ks = 0; ks < 8; ++ks)
        acc[ct] = mfma16(af[ks], ld_bf8(wr + ks * 32), acc[ct]);
    }
    unsigned short* outm = (m == 0) ? q : (m == 1) ? k : v;
#pragma unroll
    for (int ct = 0; ct < 8; ++ct) {
      const int col = ct * 16 + l16;
      const float bsc = bias[col];
#pragma unroll
      for (int r = 0; r < 4; ++r) {
        float val = acc[ct][r] + bsc;
        val = val > 0.f ? val : 0.f;
        const int n = n0 + crow0 + r;
        // node-major: ((bl*N + n)*P + p)*D + col
        outm[((size_t)(bl * NNODE + n) * PP + p) * DMODEL + col] = f2b(val);
      }
    }
  }
}

// ---------------------------------------------------------------------------
// K2: attention + MLP. One block per (bl,n); wave h owns head h entirely ->
// zero barriers inside the attention loop (wave-private LDS slices fenced with
// in-wave s_waitcnt). 3 barriers total. LDS 68 KiB -> 2 blocks/CU.
// ---------------------------------------------------------------------------
__global__ __launch_bounds__(512, 4) void attn_mlp(
    const unsigned short* __restrict__ q, const unsigned short* __restrict__ k,
    const unsigned short* __restrict__ v, const unsigned short* __restrict__ Wt,
    const float* __restrict__ b1, const float* __restrict__ b2,
    float* __restrict__ out, int b0) {
  __shared__ __align__(16) unsigned short s_m[128 * 136];  // probs scratch -> att[p][f]
  __shared__ __align__(16) unsigned short s_n[128 * 136];  // vT slices -> h1[p][f]

  const int bid = blockIdx.x, bl = bid >> 8, nn = bid & 255;
  const int bb = b0 + bl;
  const int tid = threadIdx.x;
  const int h = tid >> 6, lane = tid & 63, quad = lane >> 4, l16 = lane & 15;

  // contiguous 32 KiB slabs for this (b,n): elem (p,f) at slab + p*128 + f
  const size_t slab = (size_t)(bl * NNODE + nn) * PP * DMODEL;
  const unsigned short* qp = q + slab;
  const unsigned short* kp = k + slab;
  const unsigned short* vp = v + slab;
  const unsigned short* W1T = Wt + 98304;
  const unsigned short* W2T = Wt + 114688;

  // ---- stage vT_h into wave-private slice: s_n rows [16h,16h+16) = [f'][p]
  {
    const int ph = lane >> 1, fh = lane & 1;
#pragma unroll
    for (int i = 0; i < 4; ++i) {
      const int p = i * 32 + ph;
      const u16x8 vv = *(const u16x8*)(vp + p * DMODEL + h * 16 + fh * 8);
#pragma unroll
      for (int j = 0; j < 8; ++j)
        s_n[(h * 16 + fh * 8 + j) * 136 + p] = vv[j];
    }
  }

  // ---- attention: head h, tiled over 8 row-blocks of 16 queries
  f32x4 att[8];
#pragma unroll
  for (int i = 0; i < 8; ++i) att[i] = zero4();

  for (int mb = 0; mb < 8; ++mb) {
    // S tile: A = q rows [16mb..+16) of head h (K=16 padded to 32)
    bf16x8 aq;
    {
      bf16x8 t = ld_bf8(qp + (mb * 16 + l16) * DMODEL + h * 16 + (quad & 1) * 8);
      aq = (quad < 2) ? t : zero_bf8();
    }
    f32x4 s[8];
#pragma unroll
    for (int ct = 0; ct < 8; ++ct) {
      bf16x8 t = ld_bf8(kp + (ct * 16 + l16) * DMODEL + h * 16 + (quad & 1) * 8);
      bf16x8 bk8 = (quad < 2) ? t : zero_bf8();
      s[ct] = mfma16(aq, bk8, zero4());
    }
    // scale + causal mask + softmax (row = 16 lanes of this quad-group)
#pragma unroll
    for (int r = 0; r < 4; ++r) {
      const int prow = mb * 16 + quad * 4 + r;
      float mx = NEGINF;
#pragma unroll
      for (int ct = 0; ct < 8; ++ct) {
        const int cq = ct * 16 + l16;
        float vv = s[ct][r] * 0.25f;          // 1/sqrt(16)
        vv = (cq <= prow) ? vv : NEGINF;
        s[ct][r] = vv;
        mx = fmaxf(mx, vv);
      }
#pragma unroll
      for (int off = 1; off < 16; off <<= 1) mx = fmaxf(mx, __shfl_xor(mx, off, 64));
      float sum = 0.f;
#pragma unroll
      for (int ct = 0; ct < 8; ++ct) {
        float e = __expf(s[ct][r] - mx);
        s[ct][r] = e;
        sum += e;
      }
#pragma unroll
      for (int off = 1; off < 16; off <<= 1) sum += __shfl_xor(sum, off, 64);
      const float inv = 1.0f / sum;
#pragma unroll
      for (int ct = 0; ct < 8; ++ct) s[ct][r] *= inv;
    }
    // probs C-layout -> wave-private scratch rows [16h..+16)
#pragma unroll
    for (int ct = 0; ct < 8; ++ct)
#pragma unroll
      for (int r = 0; r < 4; ++r)
        s_m[(h * 16 + quad * 4 + r) * 136 + ct * 16 + l16] = f2b(s[ct][r]);
    // in-wave fence: DS ops are in-order per wave; wait for writes
    __asm__ volatile("s_waitcnt lgkmcnt(0)" ::: "memory");
    // PV: att_tile += probs(A) @ v_h(B from vT slice)
#pragma unroll
    for (int ks = 0; ks < 4; ++ks) {
      bf16x8 ap  = ld_bf8(&s_m[(h * 16 + l16) * 136 + ks * 32 + quad * 8]);
      bf16x8 bv8 = ld_bf8(&s_n[(h * 16 + l16) * 136 + ks * 32 + quad * 8]);
      att[mb] = mfma16(ap, bv8, att[mb]);
    }
  }

  __syncthreads();   // all heads done with scratch; s_m becomes att[p][f]
#pragma unroll
  for (int mb = 0; mb < 8; ++mb)
#pragma unroll
    for (int r = 0; r < 4; ++r)
      s_m[(mb * 16 + quad * 4 + r) * 136 + h * 16 + l16] = f2b(att[mb][r]);
  __syncthreads();

  // ---- MLP (wave h = row band [16h..+16))
  const int crow0 = h * 16 + quad * 4;
  f32x4 acc1[8];
#pragma unroll
  for (int i = 0; i < 8; ++i) acc1[i] = zero4();
  {
    bf16x8 a1[4];
#pragma unroll
    for (int ks = 0; ks < 4; ++ks)
      a1[ks] = ld_bf8(&s_m[(h * 16 + l16) * 136 + ks * 32 + quad * 8]);
#pragma unroll
    for (int ct = 0; ct < 8; ++ct) {
      const unsigned short* wr = W1T + (ct * 16 + l16) * DMODEL + quad * 8;
#pragma unroll
      for (int ks = 0; ks < 4; ++ks)
        acc1[ct] = mfma16(a1[ks], ld_bf8(wr + ks * 32), acc1[ct]);
    }
  }
#pragma unroll
  for (int ct = 0; ct < 8; ++ct) {
    const int col = ct * 16 + l16;
    const float bsc = b1[col];
#pragma unroll
    for (int r = 0; r < 4; ++r) {
      float vv = acc1[ct][r] + bsc;
      vv = vv > 0.f ? vv : 0.f;
      s_n[(crow0 + r) * 136 + col] = f2b(vv);   // h1
    }
  }
  __syncthreads();

  f32x4 acc2[8];
#pragma unroll
  for (int i = 0; i < 8; ++i) acc2[i] = zero4();
  {
    bf16x8 a2[4];
#pragma unroll
    for (int ks = 0; ks < 4; ++ks)
      a2[ks] = ld_bf8(&s_n[(h * 16 + l16) * 136 + ks * 32 + quad * 8]);
#pragma unroll
    for (int ct = 0; ct < 8; ++ct) {
      const unsigned short* wr = W2T + (ct * 16 + l16) * DMODEL + quad * 8;
#pragma unroll
      for (int ks = 0; ks < 4; ++ks)
        acc2[ct] = mfma16(a2[ks], ld_bf8(wr + ks * 32), acc2[ct]);
    }
  }
#pragma unroll
  for (int ct = 0; ct < 8; ++ct) {
    const int col = ct * 16 + l16;
    const float bsc = b2[col];
#pragma unroll
    for (int r = 0; r < 4; ++r) {
      const int row = crow0 + r;
      out[(size_t)((bb * PP + row) * NNODE + nn) * DMODEL + col] = acc2[ct][r] + bsc;
    }
  }
}

extern "C" void kernel_launch(void* const* d_in, const int* in_sizes, int n_in,
                              void* d_out, int out_size, void* d_ws, size_t ws_size,
                              hipStream_t stream) {
  const float* X   = (const float*)d_in[0];
  const float* STE = (const float*)d_in[1];
  const float* Wq  = (const float*)d_in[2];
  const float* bq  = (const float*)d_in[3];
  const float* Wk  = (const float*)d_in[4];
  const float* bk  = (const float*)d_in[5];
  const float* Wv  = (const float*)d_in[6];
  const float* bv  = (const float*)d_in[7];
  const float* W1  = (const float*)d_in[8];
  const float* b1  = (const float*)d_in[9];
  const float* W2  = (const float*)d_in[10];
  const float* b2  = (const float*)d_in[11];
  float* out = (float*)d_out;
  unsigned short* ws = (unsigned short*)d_ws;

  prep_weights<<<512, 256, 0, stream>>>(Wq, Wk, Wv, W1, W2, ws);

  // Largest batch-chunk that fits in ws: bytes = 2*(WOFF + 3*nb*PB).
  // ws_size is identical every call -> this branch is graph-capture-safe.
  int nb = 8;
  while (nb > 1 && 2ull * (WOFF + 3ull * nb * PB) > ws_size) nb >>= 1;

  unsigned short* q = ws + WOFF;
  unsigned short* kk = q + (size_t)nb * PB;
  unsigned short* vv = kk + (size_t)nb * PB;

  for (int b0 = 0; b0 < 8; b0 += nb) {
    qkv_gemm<<<nb * 256, 512, 0, stream>>>(X, STE, ws, bq, bk, bv, q, kk, vv, b0);
    attn_mlp<<<nb * 256, 512, 0, stream>>>(q, kk, vv, ws, b1, b2, out, b0);
  }
}